// Round 10
// baseline (1168.532 us; speedup 1.0000x reference)
//
#include <hip/hip_runtime.h>
#include <hip/hip_cooperative_groups.h>
#include <stdint.h>

namespace cg = cooperative_groups;

// Problem constants
#define NGRAPH 1024
#define DFEAT  256
#define KATOM  64
#define KBOND  128

// LDS layout (dynamic):
//   blds   : bond int8 feat, 4 graphs x 128 nodes x 256 B = 131072
//   c_lds  : [8][256] f32 c-state                         =   8192 @131072
//   qpk    : [8][128] u32 q bf16-pairs                    =   4096 @139264
//   bscale : [4][128] f32 per-node scales                 =   2048 @143360
//   pool   : max(gemm staging 15360, rpart 8192+csbuf 64) =  15360 @145408
#define SMEM_BYTES 160768

typedef __attribute__((ext_vector_type(4))) float accv_t;
typedef __attribute__((ext_vector_type(8))) short bfrag_t;
typedef __attribute__((ext_vector_type(4))) unsigned short upk4_t;
typedef __attribute__((ext_vector_type(8))) unsigned short upk8_t;
typedef __attribute__((ext_vector_type(4))) unsigned int u32x4;

__device__ __forceinline__ unsigned short f2bf(float f) {
    union { float f; unsigned int u; } v; v.f = f;
    return (unsigned short)((v.u + 0x7FFFu + ((v.u >> 16) & 1u)) >> 16);
}
__device__ __forceinline__ unsigned int pack2(float a, float b) {
    return (unsigned int)f2bf(a) | ((unsigned int)f2bf(b) << 16);
}
__device__ __forceinline__ float lo2f(unsigned int u) {
    union { unsigned int x; float f; } v; v.x = u << 16; return v.f;
}
__device__ __forceinline__ float hi2f(unsigned int u) {
    union { unsigned int x; float f; } v; v.x = u & 0xFFFF0000u; return v.f;
}
__device__ __forceinline__ float sigm(float x) { return 1.0f / (1.0f + __expf(-x)); }
__device__ __forceinline__ float tanh_f(float x) {
    float e = __expf(2.0f * x);
    return 1.0f - 2.0f / (e + 1.0f);
}
__device__ __forceinline__ unsigned int packq(float a, float b, float c, float d, float inv) {
    int q0 = (int)rintf(a * inv), q1 = (int)rintf(b * inv);
    int q2 = (int)rintf(c * inv), q3 = (int)rintf(d * inv);
    return (unsigned int)(q0 & 0xFF) | ((unsigned int)(q1 & 0xFF) << 8)
         | ((unsigned int)(q2 & 0xFF) << 16) | ((unsigned int)(q3 & 0xFF) << 24);
}
__device__ __forceinline__ void dec16(const unsigned int* h, float* x) {
    #pragma unroll
    for (int w4 = 0; w4 < 4; ++w4) {
        unsigned int u = h[w4];
        x[w4 * 4 + 0] = (float)((int)(u << 24) >> 24);
        x[w4 * 4 + 1] = (float)((int)(u << 16) >> 24);
        x[w4 * 4 + 2] = (float)((int)(u << 8)  >> 24);
        x[w4 * 4 + 3] = (float)((int)u >> 24);
    }
}

// ---------------------------------------------------------------------------
// Prep: Wc[set][n][k] (bf16), bsum = b_ih + b_hh. set0 = atom, set1 = bond.
// ---------------------------------------------------------------------------
__global__ __launch_bounds__(512) void k_prep(
    const float* __restrict__ WihA, const float* __restrict__ WhhA,
    const float* __restrict__ bihA, const float* __restrict__ bhhA,
    const float* __restrict__ WihB, const float* __restrict__ WhhB,
    const float* __restrict__ bihB, const float* __restrict__ bhhB,
    unsigned short* __restrict__ Wc, float* __restrict__ bsum)
{
    int bid = blockIdx.x;
    int set = bid >> 10;
    int n   = bid & 1023;
    int k   = threadIdx.x;
    const float* Wih = set ? WihB : WihA;
    const float* Whh = set ? WhhB : WhhA;
    float w = Wih[(size_t)n * 512 + k];
    if (k < 256) w += Whh[(size_t)n * 256 + k];
    Wc[((size_t)(set << 10) + n) * 512 + k] = f2bf(w);
    if (k == 0) {
        const float* bih = set ? bihB : bihA;
        const float* bhh = set ? bhhB : bhhA;
        bsum[(set << 10) + n] = bih[n] + bhh[n];
    }
}

// ---------------------------------------------------------------------------
// Persistent cooperative kernel: 256 blocks x 512 threads, 1 block/CU.
// Block b: atom graphs 4b..4b+3 (feat int8 in REGISTERS: 32 u32 + 8 scales
// per lane) and bond graphs 4b..4b+3 (feat int8 in LDS, 128 KB, linear
// lane-addressable). Wave w: graph gq=w>>1, half=w&1; lane (g,s): nodes
// {half*NPH + g + 4j}, dims [16s,16s+16). Per iter: [GEMM->gridsync] ->
// LSTM -> bond attn -> atom attn -> gridsync. feat read from HBM once.
// ---------------------------------------------------------------------------
__global__ __launch_bounds__(512) void k_persist(
    const float* __restrict__ featA, const float* __restrict__ featB,
    const unsigned short* __restrict__ Wc, const float* __restrict__ bsum,
    const float* __restrict__ fg, float* __restrict__ gates,
    float* __restrict__ hr, float* __restrict__ out)
{
    extern __shared__ char smem[];
    unsigned int*   blds   = (unsigned int*)smem;
    float*          c_lds  = (float*)(smem + 131072);
    unsigned int*   qpk    = (unsigned int*)(smem + 139264);
    float*          bscale = (float*)(smem + 143360);
    char*           pool   = smem + 145408;
    unsigned short* sA     = (unsigned short*)pool;            // [128][40]
    unsigned short* sB     = (unsigned short*)(pool + 10240);  // [64][40]
    float*          rpart  = (float*)pool;                     // [8][256]
    float*          csbuf  = (float*)(pool + 8192);            // [8][2]

    const int b    = blockIdx.x;
    const int t    = threadIdx.x;
    const int w    = t >> 6;
    const int lane = t & 63;
    const int g    = lane >> 4;
    const int s    = lane & 15;
    const int gq   = w >> 1;       // local graph 0..3
    const int half = w & 1;
    const int l15  = lane & 15;
    const int khalf = (lane >> 4) * 8;
    const int r4    = (lane >> 4) * 4;

    // ---------------- prologue: atom feat -> regs (int8) ----------------
    unsigned int ar[8][4];
    float asc[8];
    {
        const float* base = featA + (size_t)(4 * b + gq) * 64 * 256;
        #pragma unroll
        for (int j = 0; j < 8; ++j) {
            int node = half * 32 + g + 4 * j;
            const float* p = base + (size_t)node * 256 + s * 16;
            accv_t v0 = __builtin_nontemporal_load((const accv_t*)p);
            accv_t v1 = __builtin_nontemporal_load((const accv_t*)(p + 4));
            accv_t v2 = __builtin_nontemporal_load((const accv_t*)(p + 8));
            accv_t v3 = __builtin_nontemporal_load((const accv_t*)(p + 12));
            float m = 0.0f;
            #pragma unroll
            for (int k = 0; k < 4; ++k)
                m = fmaxf(m, fmaxf(fmaxf(fabsf(v0[k]), fabsf(v1[k])),
                                   fmaxf(fabsf(v2[k]), fabsf(v3[k]))));
            m = fmaxf(m, __shfl_xor(m, 1));
            m = fmaxf(m, __shfl_xor(m, 2));
            m = fmaxf(m, __shfl_xor(m, 4));
            m = fmaxf(m, __shfl_xor(m, 8));
            float inv = (m > 0.0f) ? 127.0f / m : 0.0f;
            asc[j] = m * (1.0f / 127.0f);
            ar[j][0] = packq(v0[0], v0[1], v0[2], v0[3], inv);
            ar[j][1] = packq(v1[0], v1[1], v1[2], v1[3], inv);
            ar[j][2] = packq(v2[0], v2[1], v2[2], v2[3], inv);
            ar[j][3] = packq(v3[0], v3[1], v3[2], v3[3], inv);
        }
    }
    // ---------------- prologue: bond feat -> LDS (int8) ----------------
    {
        const float* base = featB + (size_t)(4 * b + gq) * 128 * 256;
        #pragma unroll
        for (int j = 0; j < 16; ++j) {
            int node = half * 64 + g + 4 * j;
            const float* p = base + (size_t)node * 256 + s * 16;
            accv_t v0 = __builtin_nontemporal_load((const accv_t*)p);
            accv_t v1 = __builtin_nontemporal_load((const accv_t*)(p + 4));
            accv_t v2 = __builtin_nontemporal_load((const accv_t*)(p + 8));
            accv_t v3 = __builtin_nontemporal_load((const accv_t*)(p + 12));
            float m = 0.0f;
            #pragma unroll
            for (int k = 0; k < 4; ++k)
                m = fmaxf(m, fmaxf(fmaxf(fabsf(v0[k]), fabsf(v1[k])),
                                   fmaxf(fabsf(v2[k]), fabsf(v3[k]))));
            m = fmaxf(m, __shfl_xor(m, 1));
            m = fmaxf(m, __shfl_xor(m, 2));
            m = fmaxf(m, __shfl_xor(m, 4));
            m = fmaxf(m, __shfl_xor(m, 8));
            float inv = (m > 0.0f) ? 127.0f / m : 0.0f;
            u32x4 u;
            u[0] = packq(v0[0], v0[1], v0[2], v0[3], inv);
            u[1] = packq(v1[0], v1[1], v1[2], v1[3], inv);
            u[2] = packq(v2[0], v2[1], v2[2], v2[3], inv);
            u[3] = packq(v3[0], v3[1], v3[2], v3[3], inv);
            *(u32x4*)&blds[gq * 8192 + node * 64 + s * 4] = u;
            if (s == 0) bscale[gq * 128 + node] = m * (1.0f / 127.0f);
        }
    }
    __syncthreads();

    for (int it = 0; it < 6; ++it) {
        if (it > 0) {
            // ============ GEMM phase: 256 tiles of 128x64, K=512 ===========
            const int mtile = b >> 4, ntile = b & 15;
            const int mbase = mtile * 128, nbase = ntile * 64;
            const int gset  = (mtile >= 8);
            accv_t acc[2][2];
            #pragma unroll
            for (int i = 0; i < 2; ++i)
                #pragma unroll
                for (int j = 0; j < 2; ++j)
                    acc[i][j] = (accv_t){0.f, 0.f, 0.f, 0.f};
            for (int k0 = 0; k0 < 512; k0 += 32) {
                #pragma unroll
                for (int i = 0; i < 2; ++i) {
                    int idx = t + 512 * i;              // 1024 float4
                    int row = idx >> 3;
                    int kc  = (idx & 7) * 4;
                    float4 a = *(const float4*)&hr[(size_t)(mbase + row) * 512 + k0 + kc];
                    *(upk4_t*)&sA[row * 40 + kc] =
                        (upk4_t){f2bf(a.x), f2bf(a.y), f2bf(a.z), f2bf(a.w)};
                }
                if (t < 256) {                          // 256 ushort8
                    int row = t >> 2;
                    int kc  = (t & 3) * 8;
                    *(upk8_t*)&sB[row * 40 + kc] =
                        *(const upk8_t*)&Wc[((size_t)(gset << 10) + nbase + row) * 512 + k0 + kc];
                }
                __syncthreads();
                const int wr = w >> 1, wcq = w & 1;
                bfrag_t a_f[2], b_f[2];
                #pragma unroll
                for (int i = 0; i < 2; ++i)
                    a_f[i] = *(const bfrag_t*)&sA[(wr * 32 + i * 16 + l15) * 40 + khalf];
                #pragma unroll
                for (int j = 0; j < 2; ++j)
                    b_f[j] = *(const bfrag_t*)&sB[(wcq * 32 + j * 16 + l15) * 40 + khalf];
                #pragma unroll
                for (int i = 0; i < 2; ++i)
                    #pragma unroll
                    for (int j = 0; j < 2; ++j)
                        acc[i][j] = __builtin_amdgcn_mfma_f32_16x16x32_bf16(a_f[i], b_f[j], acc[i][j], 0, 0, 0);
                __syncthreads();
            }
            {
                const int wr = w >> 1, wcq = w & 1;
                #pragma unroll
                for (int i = 0; i < 2; ++i) {
                    #pragma unroll
                    for (int j = 0; j < 2; ++j) {
                        int col = nbase + wcq * 32 + j * 16 + l15;
                        float bs = bsum[(gset << 10) + col];
                        #pragma unroll
                        for (int v = 0; v < 4; ++v) {
                            int row = mbase + wr * 32 + i * 16 + r4 + v;
                            gates[(size_t)row * 1024 + col] = acc[i][j][v] + bs;
                        }
                    }
                }
            }
            __threadfence();
            cg::this_grid().sync();
        }

        // ================= LSTM phase (block-local graphs) =================
        #pragma unroll
        for (int p = 0; p < 2; ++p) {
            int idx = t + 512 * p;          // 0..1023 = 8 slots x 128 pairs
            int lgx = idx >> 7;
            int pr  = idx & 127;
            int d0  = pr * 2;
            int set = (lgx >= 4);
            int row = set ? (1024 + 4 * b + (lgx - 4)) : (4 * b + lgx);
            float gi0, gi1, gf0, gf1, gg0, gg1, go0, go1, c0, c1;
            if (it == 0) {
                const float* bs = bsum + (set << 10);
                gi0 = bs[d0];       gi1 = bs[d0 + 1];
                gf0 = bs[256 + d0]; gf1 = bs[256 + d0 + 1];
                gg0 = bs[512 + d0]; gg1 = bs[512 + d0 + 1];
                go0 = bs[768 + d0]; go1 = bs[768 + d0 + 1];
                c0 = 0.f; c1 = 0.f;
            } else {
                const float* gp = gates + (size_t)row * 1024;
                float2 a0 = *(const float2*)(gp + d0);
                float2 a1 = *(const float2*)(gp + 256 + d0);
                float2 a2 = *(const float2*)(gp + 512 + d0);
                float2 a3 = *(const float2*)(gp + 768 + d0);
                gi0 = a0.x; gi1 = a0.y; gf0 = a1.x; gf1 = a1.y;
                gg0 = a2.x; gg1 = a2.y; go0 = a3.x; go1 = a3.y;
                c0 = c_lds[lgx * 256 + d0];
                c1 = c_lds[lgx * 256 + d0 + 1];
            }
            float cn0 = sigm(gf0) * c0 + sigm(gi0) * tanh_f(gg0);
            float cn1 = sigm(gf1) * c1 + sigm(gi1) * tanh_f(gg1);
            float h0 = sigm(go0) * tanh_f(cn0);
            float h1 = sigm(go1) * tanh_f(cn1);
            c_lds[lgx * 256 + d0]     = cn0;
            c_lds[lgx * 256 + d0 + 1] = cn1;
            qpk[lgx * 128 + pr] = pack2(h0, h1);
            if (it == 5) {
                *(float2*)&out[(size_t)(4 * b + (lgx & 3)) * 1152 + (set ? 512 : 0) + d0] =
                    make_float2(h0, h1);
            } else {
                *(float2*)&hr[(size_t)row * 512 + d0] = make_float2(h0, h1);
            }
        }
        __syncthreads();

        // ================= ATTN: bond (feat in LDS int8) ===================
        {
            float qr[16];
            #pragma unroll
            for (int mm = 0; mm < 8; ++mm) {
                unsigned int u = qpk[(4 + gq) * 128 + s * 8 + mm];
                qr[2 * mm] = lo2f(u); qr[2 * mm + 1] = hi2f(u);
            }
            float C = 0.f, S = 0.f;
            float r[16];
            #pragma unroll
            for (int k = 0; k < 16; ++k) r[k] = 0.f;
            #pragma unroll
            for (int j = 0; j < 16; ++j) {
                int node = half * 64 + g + 4 * j;
                u32x4 hx = *(const u32x4*)&blds[gq * 8192 + node * 64 + s * 4];
                float sc = bscale[gq * 128 + node];
                float x[16];
                dec16((const unsigned int*)&hx, x);
                float pdot = 0.f;
                #pragma unroll
                for (int k = 0; k < 16; ++k) pdot += x[k] * qr[k];
                pdot += __shfl_xor(pdot, 1);
                pdot += __shfl_xor(pdot, 2);
                pdot += __shfl_xor(pdot, 4);
                pdot += __shfl_xor(pdot, 8);
                float e = pdot * sc;
                float wj = (j == 0) ? 1.0f : __expf(e - C);
                if (j == 0) C = e;
                S += wj;
                float wl = wj * sc;
                #pragma unroll
                for (int k = 0; k < 16; ++k) r[k] += wl * x[k];
            }
            // wave merge over the 4 g-groups (pivot-reconciled)
            float M = C;
            M = fmaxf(M, __shfl_xor(M, 16));
            M = fmaxf(M, __shfl_xor(M, 32));
            float f = __expf(C - M);
            S *= f;
            S += __shfl_xor(S, 16);
            S += __shfl_xor(S, 32);
            #pragma unroll
            for (int k = 0; k < 16; ++k) {
                r[k] *= f;
                r[k] += __shfl_xor(r[k], 16);
                r[k] += __shfl_xor(r[k], 32);
            }
            if (g == 0) {
                #pragma unroll
                for (int k = 0; k < 16; k += 4)
                    *(float4*)&rpart[w * 256 + s * 16 + k] =
                        make_float4(r[k], r[k + 1], r[k + 2], r[k + 3]);
                if (s == 0) { csbuf[w * 2] = M; csbuf[w * 2 + 1] = S; }
            }
        }
        __syncthreads();
        if ((w & 1) == 0) {   // merge graph bg = w>>1 (partials w, w+1)
            int bg = w >> 1;
            float M0 = csbuf[(2 * bg) * 2],     S0 = csbuf[(2 * bg) * 2 + 1];
            float M1 = csbuf[(2 * bg + 1) * 2], S1 = csbuf[(2 * bg + 1) * 2 + 1];
            float Mx = fmaxf(M0, M1);
            float f0 = __expf(M0 - Mx), f1 = __expf(M1 - Mx);
            float Sx = S0 * f0 + S1 * f1;
            int d4 = lane * 4;
            float4 p0 = *(const float4*)&rpart[(2 * bg) * 256 + d4];
            float4 p1 = *(const float4*)&rpart[(2 * bg + 1) * 256 + d4];
            float4 rv = make_float4((p0.x * f0 + p1.x * f1) / Sx, (p0.y * f0 + p1.y * f1) / Sx,
                                    (p0.z * f0 + p1.z * f1) / Sx, (p0.w * f0 + p1.w * f1) / Sx);
            if (it == 5) *(float4*)&out[(size_t)(4 * b + bg) * 1152 + 768 + d4] = rv;
            else         *(float4*)&hr[(size_t)(1024 + 4 * b + bg) * 512 + 256 + d4] = rv;
        }
        __syncthreads();

        // ================= ATTN: atom (feat in regs int8) ==================
        {
            float qr[16];
            #pragma unroll
            for (int mm = 0; mm < 8; ++mm) {
                unsigned int u = qpk[gq * 128 + s * 8 + mm];
                qr[2 * mm] = lo2f(u); qr[2 * mm + 1] = hi2f(u);
            }
            float C = 0.f, S = 0.f;
            float r[16];
            #pragma unroll
            for (int k = 0; k < 16; ++k) r[k] = 0.f;
            #pragma unroll
            for (int j = 0; j < 8; ++j) {
                float sc = asc[j];
                float x[16];
                dec16(ar[j], x);
                float pdot = 0.f;
                #pragma unroll
                for (int k = 0; k < 16; ++k) pdot += x[k] * qr[k];
                pdot += __shfl_xor(pdot, 1);
                pdot += __shfl_xor(pdot, 2);
                pdot += __shfl_xor(pdot, 4);
                pdot += __shfl_xor(pdot, 8);
                float e = pdot * sc;
                float wj = (j == 0) ? 1.0f : __expf(e - C);
                if (j == 0) C = e;
                S += wj;
                float wl = wj * sc;
                #pragma unroll
                for (int k = 0; k < 16; ++k) r[k] += wl * x[k];
            }
            float M = C;
            M = fmaxf(M, __shfl_xor(M, 16));
            M = fmaxf(M, __shfl_xor(M, 32));
            float f = __expf(C - M);
            S *= f;
            S += __shfl_xor(S, 16);
            S += __shfl_xor(S, 32);
            #pragma unroll
            for (int k = 0; k < 16; ++k) {
                r[k] *= f;
                r[k] += __shfl_xor(r[k], 16);
                r[k] += __shfl_xor(r[k], 32);
            }
            if (g == 0) {
                #pragma unroll
                for (int k = 0; k < 16; k += 4)
                    *(float4*)&rpart[w * 256 + s * 16 + k] =
                        make_float4(r[k], r[k + 1], r[k + 2], r[k + 3]);
                if (s == 0) { csbuf[w * 2] = M; csbuf[w * 2 + 1] = S; }
            }
        }
        __syncthreads();
        if ((w & 1) == 0) {   // merge atom graph ag = w>>1
            int ag = w >> 1;
            float M0 = csbuf[(2 * ag) * 2],     S0 = csbuf[(2 * ag) * 2 + 1];
            float M1 = csbuf[(2 * ag + 1) * 2], S1 = csbuf[(2 * ag + 1) * 2 + 1];
            float Mx = fmaxf(M0, M1);
            float f0 = __expf(M0 - Mx), f1 = __expf(M1 - Mx);
            float Sx = S0 * f0 + S1 * f1;
            int d4 = lane * 4;
            float4 p0 = *(const float4*)&rpart[(2 * ag) * 256 + d4];
            float4 p1 = *(const float4*)&rpart[(2 * ag + 1) * 256 + d4];
            float4 rv = make_float4((p0.x * f0 + p1.x * f1) / Sx, (p0.y * f0 + p1.y * f1) / Sx,
                                    (p0.z * f0 + p1.z * f1) / Sx, (p0.w * f0 + p1.w * f1) / Sx);
            if (it == 5) *(float4*)&out[(size_t)(4 * b + ag) * 1152 + 256 + d4] = rv;
            else         *(float4*)&hr[(size_t)(4 * b + ag) * 512 + 256 + d4] = rv;
        }
        if (it < 5) { __threadfence(); cg::this_grid().sync(); }
    }

    // ---------------- feat_global tail ----------------
    {
        int gr = t >> 7, c = t & 127;
        out[(size_t)(4 * b + gr) * 1152 + 1024 + c] = fg[(size_t)(4 * b + gr) * 128 + c];
    }
}

// ===========================================================================
// Fallback pipeline (R9, proven 223 us): used only if coop launch fails.
// ===========================================================================
__global__ __launch_bounds__(256) void k_cvt(
    const float* __restrict__ fA, const float* __restrict__ fB,
    unsigned int* __restrict__ oA, unsigned int* __restrict__ oB,
    float* __restrict__ scA, float* __restrict__ scB)
{
    int wid  = blockIdx.x * 4 + (threadIdx.x >> 6);
    int lane = threadIdx.x & 63;
    int grp  = lane >> 3;
    #pragma unroll 2
    for (int n = wid; n < 65536; n += 4096) {
        accv_t v = __builtin_nontemporal_load((const accv_t*)(fA + (size_t)n * 256) + lane);
        float m = fmaxf(fmaxf(fabsf(v[0]), fabsf(v[1])), fmaxf(fabsf(v[2]), fabsf(v[3])));
        m = fmaxf(m, __shfl_xor(m, 1));
        m = fmaxf(m, __shfl_xor(m, 2));
        m = fmaxf(m, __shfl_xor(m, 4));
        float inv = (m > 0.0f) ? 127.0f / m : 0.0f;
        oA[(size_t)n * 64 + lane] = packq(v[0], v[1], v[2], v[3], inv);
        if ((lane & 7) == 0) scA[(size_t)n * 8 + grp] = m * (1.0f / 127.0f);
    }
    #pragma unroll 2
    for (int n = wid; n < 131072; n += 4096) {
        accv_t v = __builtin_nontemporal_load((const accv_t*)(fB + (size_t)n * 256) + lane);
        float m = fmaxf(fmaxf(fabsf(v[0]), fabsf(v[1])), fmaxf(fabsf(v[2]), fabsf(v[3])));
        m = fmaxf(m, __shfl_xor(m, 1));
        m = fmaxf(m, __shfl_xor(m, 2));
        m = fmaxf(m, __shfl_xor(m, 4));
        float inv = (m > 0.0f) ? 127.0f / m : 0.0f;
        oB[(size_t)n * 64 + lane] = packq(v[0], v[1], v[2], v[3], inv);
        if ((lane & 7) == 0) scB[(size_t)n * 8 + grp] = m * (1.0f / 127.0f);
    }
}

__global__ __launch_bounds__(256) void k_gemm(
    const float* __restrict__ hr, const unsigned short* __restrict__ Wc,
    const float* __restrict__ bsum, float* __restrict__ gates)
{
    __shared__ unsigned short sA[64 * 40];
    __shared__ unsigned short sB[128 * 40];
    int set   = blockIdx.x >> 7;
    int qq    = blockIdx.x & 127;
    int mbase = (qq >> 3) * 64;
    int nbase = (qq & 7) * 128;
    int t     = threadIdx.x;
    int lane  = t & 63;
    int w     = t >> 6;
    int wrow  = (w >> 1) * 32;
    int wcol  = (w & 1) * 64;
    int l15   = lane & 15;
    int khalf = (lane >> 4) * 8;
    const float* A           = hr + (size_t)(set << 10) * 512;
    const unsigned short* Bm = Wc + (size_t)(set << 10) * 512;
    accv_t acc[2][4];
    #pragma unroll
    for (int i = 0; i < 2; ++i)
        #pragma unroll
        for (int j = 0; j < 4; ++j)
            acc[i][j] = (accv_t){0.f, 0.f, 0.f, 0.f};
    for (int k0 = 0; k0 < 512; k0 += 32) {
        #pragma unroll
        for (int i = 0; i < 2; ++i) {
            int idx4 = t + 256 * i;
            int row  = idx4 >> 3;
            int kc   = (idx4 & 7) * 4;
            const float4 a = *(const float4*)&A[(size_t)(mbase + row) * 512 + k0 + kc];
            *(upk4_t*)&sA[row * 40 + kc] =
                (upk4_t){f2bf(a.x), f2bf(a.y), f2bf(a.z), f2bf(a.w)};
        }
        #pragma unroll
        for (int i = 0; i < 2; ++i) {
            int idx8 = t + 256 * i;
            int row  = idx8 >> 2;
            int kc   = (idx8 & 3) * 8;
            *(upk8_t*)&sB[row * 40 + kc] =
                *(const upk8_t*)&Bm[(size_t)(nbase + row) * 512 + k0 + kc];
        }
        __syncthreads();
        bfrag_t a_f[2], b_f[4];
        #pragma unroll
        for (int i = 0; i < 2; ++i)
            a_f[i] = *(const bfrag_t*)&sA[(wrow + i * 16 + l15) * 40 + khalf];
        #pragma unroll
        for (int j = 0; j < 4; ++j)
            b_f[j] = *(const bfrag_t*)&sB[(wcol + j * 16 + l15) * 40 + khalf];
        #pragma unroll
        for (int i = 0; i < 2; ++i)
            #pragma unroll
            for (int j = 0; j < 4; ++j)
                acc[i][j] = __builtin_amdgcn_mfma_f32_16x16x32_bf16(a_f[i], b_f[j], acc[i][j], 0, 0, 0);
        __syncthreads();
    }
    int r4 = (lane >> 4) * 4;
    #pragma unroll
    for (int i = 0; i < 2; ++i) {
        #pragma unroll
        for (int j = 0; j < 4; ++j) {
            int col  = nbase + wcol + j * 16 + l15;
            float bs = bsum[(set << 10) + col];
            #pragma unroll
            for (int v = 0; v < 4; ++v) {
                int row = mbase + wrow + i * 16 + r4 + v;
                gates[((size_t)(set << 10) + row) * 1024 + col] = acc[i][j][v] + bs;
            }
        }
    }
}

template <int MODE, bool LAST>
__global__ __launch_bounds__(256) void k_attn(
    const float* __restrict__ featA, const float* __restrict__ featB,
    const unsigned int* __restrict__ i8A, const unsigned int* __restrict__ i8B,
    const float* __restrict__ scA, const float* __restrict__ scB,
    const float* __restrict__ gates, const float* __restrict__ bsum,
    float* __restrict__ hr, float* __restrict__ cst,
    const float* __restrict__ fgp, float* __restrict__ outp, int iter)
{
    __shared__ float qv[256];
    __shared__ float sw_s[16], cw_s[16];
    __shared__ float racc_s[16][260];
    int bid = blockIdx.x;
    int set = (bid < 1024) ? 1 : 0;
    int b   = bid & 1023;
    int K   = set ? KBOND : KATOM;
    int t = threadIdx.x;
    size_t sb = (size_t)(set << 10) + b;
    size_t ob = (size_t)b * 1152 + (set ? 512 : 0);
    {
        int d = t;
        float gi, gf, gg, go, cold;
        if (iter == 0) {
            gi = bsum[(set << 10) + d];
            gf = bsum[(set << 10) + 256 + d];
            gg = bsum[(set << 10) + 512 + d];
            go = bsum[(set << 10) + 768 + d];
            cold = 0.0f;
        } else {
            const float* gp = gates + sb * 1024;
            gi = gp[d]; gf = gp[256 + d]; gg = gp[512 + d]; go = gp[768 + d];
            cold = cst[sb * 256 + d];
        }
        float cn = sigm(gf) * cold + sigm(gi) * tanh_f(gg);
        float h  = sigm(go) * tanh_f(cn);
        if (LAST) { outp[ob + d] = h; }
        else      { cst[sb * 256 + d] = cn; hr[sb * 512 + d] = h; }
        qv[d] = h;
    }
    __syncthreads();
    int lane = t & 63;
    int wv   = t >> 6;
    int g    = lane >> 4;
    int s    = lane & 15;
    int npw  = K >> 2;
    int nq   = npw >> 2;
    int node0 = wv * npw + g;
    float C = 0.0f, sacc = 0.0f;
    int pid = (wv << 2) | g;
    if (MODE == 1) {
        const unsigned int* fb = (set ? i8B : i8A)
                               + ((size_t)b * K + node0) * 64 + s * 4;
        const float* scp = (set ? scB : scA)
                         + ((size_t)b * K + node0) * 8 + (s >> 1);
        float qr[16];
        #pragma unroll
        for (int j = 0; j < 16; ++j) qr[j] = qv[s * 16 + j];
        float r[16];
        #pragma unroll
        for (int j = 0; j < 16; ++j) r[j] = 0.0f;
        #pragma unroll 4
        for (int qd = 0; qd < nq; ++qd) {
            u32x4 hx = *(const u32x4*)(fb + (size_t)qd * 256);
            float sc = scp[(size_t)qd * 32];
            float x[16];
            dec16((const unsigned int*)&hx, x);
            float e = 0.0f;
            #pragma unroll
            for (int j = 0; j < 16; ++j) e += x[j] * qr[j];
            e *= sc;
            e += __shfl_xor(e, 1);
            e += __shfl_xor(e, 2);
            e += __shfl_xor(e, 4);
            e += __shfl_xor(e, 8);
            float w = (qd == 0) ? 1.0f : __expf(e - C);
            if (qd == 0) C = e;
            sacc += w;
            float wl = w * sc;
            #pragma unroll
            for (int j = 0; j < 16; ++j) r[j] += wl * x[j];
        }
        #pragma unroll
        for (int j = 0; j < 16; j += 4)
            *(float4*)&racc_s[pid][s * 16 + j] = *(float4*)&r[j];
    } else {
        const float* feat = set ? featB : featA;
        const float* fb = feat + ((size_t)b * K + node0) * 256 + s * 4;
        float4 q0 = *(const float4*)&qv[s*4];
        float4 q1 = *(const float4*)&qv[64  + s*4];
        float4 q2 = *(const float4*)&qv[128 + s*4];
        float4 q3 = *(const float4*)&qv[192 + s*4];
        float4 r0 = make_float4(0.f,0.f,0.f,0.f), r1 = r0, r2 = r0, r3 = r0;
        #pragma unroll 2
        for (int qd = 0; qd < nq; ++qd) {
            const float* p = fb + (size_t)qd * 1024;
            float4 x0 = *(const float4*)(p);
            float4 x1 = *(const float4*)(p + 64);
            float4 x2 = *(const float4*)(p + 128);
            float4 x3 = *(const float4*)(p + 192);
            float e = x0.x*q0.x + x0.y*q0.y + x0.z*q0.z + x0.w*q0.w
                    + x1.x*q1.x + x1.y*q1.y + x1.z*q1.z + x1.w*q1.w
                    + x2.x*q2.x + x2.y*q2.y + x2.z*q2.z + x2.w*q2.w
                    + x3.x*q3.x + x3.y*q3.y + x3.z*q3.z + x3.w*q3.w;
            e += __shfl_xor(e, 1); e += __shfl_xor(e, 2);
            e += __shfl_xor(e, 4); e += __shfl_xor(e, 8);
            float w = (qd == 0) ? 1.0f : __expf(e - C);
            if (qd == 0) C = e;
            sacc += w;
            r0.x += w*x0.x; r0.y += w*x0.y; r0.z += w*x0.z; r0.w += w*x0.w;
            r1.x += w*x1.x; r1.y += w*x1.y; r1.z += w*x1.z; r1.w += w*x1.w;
            r2.x += w*x2.x; r2.y += w*x2.y; r2.z += w*x2.z; r2.w += w*x2.w;
            r3.x += w*x3.x; r3.y += w*x3.y; r3.z += w*x3.z; r3.w += w*x3.w;
        }
        *(float4*)&racc_s[pid][s*4]       = r0;
        *(float4*)&racc_s[pid][64  + s*4] = r1;
        *(float4*)&racc_s[pid][128 + s*4] = r2;
        *(float4*)&racc_s[pid][192 + s*4] = r3;
    }
    if (s == 0) { sw_s[pid] = sacc; cw_s[pid] = C; }
    __syncthreads();
    {
        float Cm = cw_s[0];
        #pragma unroll
        for (int p2 = 1; p2 < 16; ++p2) Cm = fmaxf(Cm, cw_s[p2]);
        float S = 0.0f, r = 0.0f;
        #pragma unroll
        for (int p2 = 0; p2 < 16; ++p2) {
            float f = __expf(cw_s[p2] - Cm);
            S += sw_s[p2] * f;
            r += racc_s[p2][t] * f;
        }
        float rv = r / S;
        if (LAST) {
            outp[ob + 256 + t] = rv;
            if (set && t < 128)
                outp[(size_t)b * 1152 + 1024 + t] = fgp[(size_t)b * 128 + t];
        } else {
            hr[sb * 512 + 256 + t] = rv;
        }
    }
}

extern "C" void kernel_launch(void* const* d_in, const int* in_sizes, int n_in,
                              void* d_out, int out_size, void* d_ws, size_t ws_size,
                              hipStream_t stream) {
    const float* feat_atom   = (const float*)d_in[0];
    const float* feat_bond   = (const float*)d_in[2];
    const float* feat_global = (const float*)d_in[4];
    const float* WihA = (const float*)d_in[5];
    const float* WhhA = (const float*)d_in[6];
    const float* bihA = (const float*)d_in[7];
    const float* bhhA = (const float*)d_in[8];
    const float* WihB = (const float*)d_in[9];
    const float* WhhB = (const float*)d_in[10];
    const float* bihB = (const float*)d_in[11];
    const float* bhhB = (const float*)d_in[12];
    float* out = (float*)d_out;

    char* ws = (char*)d_ws;
    unsigned short* Wc = (unsigned short*)(ws + 0);           // 2 MB
    float* bsum  = (float*)(ws + 2097152);                    // 8 KB
    float* gates = (float*)(ws + 2105344);                    // 8 MB
    float* hr    = (float*)(ws + 10493952);                   // 4 MB
    float* cst   = (float*)(ws + 14688256);                   // 2 MB (fallback)
    unsigned int* i8A = (unsigned int*)(ws + 16785408);       // 16 MB (fallback)
    unsigned int* i8B = (unsigned int*)(ws + 33562624);       // 32 MB (fallback)
    float* scA = (float*)(ws + 67117056);                     // 2 MB (fallback)
    float* scB = (float*)(ws + 69214208);                     // 4 MB (fallback)
    const size_t WS_FB = 69214208 + 4194304;
    (void)in_sizes; (void)n_in; (void)out_size;

    k_prep<<<2048, 512, 0, stream>>>(WihA, WhhA, bihA, bhhA,
                                     WihB, WhhB, bihB, bhhB, Wc, bsum);

    bool coop_ok = false;
    {
        hipError_t ea = hipFuncSetAttribute((const void*)k_persist,
            hipFuncAttributeMaxDynamicSharedMemorySize, SMEM_BYTES);
        if (ea == hipSuccess) {
            void* args[] = { (void*)&feat_atom, (void*)&feat_bond, (void*)&Wc,
                             (void*)&bsum, (void*)&feat_global, (void*)&gates,
                             (void*)&hr, (void*)&out };
            hipError_t eb = hipLaunchCooperativeKernel((const void*)k_persist,
                dim3(256), dim3(512), args, (unsigned int)SMEM_BYTES, stream);
            coop_ok = (eb == hipSuccess);
        }
    }
    if (!coop_ok) {
        bool i8ok = (ws_size >= WS_FB);
        if (i8ok) {
            k_cvt<<<1024, 256, 0, stream>>>(feat_atom, feat_bond, i8A, i8B, scA, scB);
            k_attn<1, false><<<2048, 256, 0, stream>>>(feat_atom, feat_bond, i8A, i8B,
                                                       scA, scB, gates, bsum, hr, cst,
                                                       feat_global, out, 0);
            for (int it = 1; it < 5; ++it) {
                k_gemm<<<256, 256, 0, stream>>>(hr, Wc, bsum, gates);
                k_attn<1, false><<<2048, 256, 0, stream>>>(feat_atom, feat_bond, i8A, i8B,
                                                           scA, scB, gates, bsum, hr, cst,
                                                           feat_global, out, it);
            }
            k_gemm<<<256, 256, 0, stream>>>(hr, Wc, bsum, gates);
            k_attn<1, true><<<2048, 256, 0, stream>>>(feat_atom, feat_bond, i8A, i8B,
                                                      scA, scB, gates, bsum, hr, cst,
                                                      feat_global, out, 5);
        } else {
            k_attn<2, false><<<2048, 256, 0, stream>>>(feat_atom, feat_bond, 0, 0, 0, 0,
                                                       gates, bsum, hr, cst,
                                                       feat_global, out, 0);
            for (int it = 1; it < 5; ++it) {
                k_gemm<<<256, 256, 0, stream>>>(hr, Wc, bsum, gates);
                k_attn<2, false><<<2048, 256, 0, stream>>>(feat_atom, feat_bond, 0, 0, 0, 0,
                                                           gates, bsum, hr, cst,
                                                           feat_global, out, it);
            }
            k_gemm<<<256, 256, 0, stream>>>(hr, Wc, bsum, gates);
            k_attn<2, true><<<2048, 256, 0, stream>>>(feat_atom, feat_bond, 0, 0, 0, 0,
                                                      gates, bsum, hr, cst,
                                                      feat_global, out, 5);
        }
    }
}

// Round 11
// 184.862 us; speedup vs baseline: 6.3211x; 6.3211x over previous
//
#include <hip/hip_runtime.h>
#include <stdint.h>

// Problem constants (from reference)
#define NGRAPH 1024
#define DFEAT  256     // D
#define KATOM  64      // atoms per graph
#define KBOND  128     // bonds per graph

typedef __attribute__((ext_vector_type(4))) float accv_t;     // MFMA C/D (4 fp32)
typedef __attribute__((ext_vector_type(8))) short bfrag_t;    // MFMA A/B (8 bf16)
typedef __attribute__((ext_vector_type(4))) unsigned short upk4_t;
typedef __attribute__((ext_vector_type(8))) unsigned short upk8_t;
typedef __attribute__((ext_vector_type(4))) unsigned int u32x4;

__device__ __forceinline__ unsigned short f2bf(float f) {
    union { float f; unsigned int u; } v; v.f = f;
    return (unsigned short)((v.u + 0x7FFFu + ((v.u >> 16) & 1u)) >> 16);
}
__device__ __forceinline__ float bf2f(unsigned short h) {
    union { unsigned int u; float f; } v; v.u = ((unsigned int)h) << 16;
    return v.f;
}
__device__ __forceinline__ float sigm(float x) { return 1.0f / (1.0f + __expf(-x)); }
__device__ __forceinline__ float tanh_f(float x) {
    float e = __expf(2.0f * x);
    return 1.0f - 2.0f / (e + 1.0f);
}
__device__ __forceinline__ unsigned int packq(float a, float b, float c, float d, float inv) {
    int q0 = (int)rintf(a * inv), q1 = (int)rintf(b * inv);
    int q2 = (int)rintf(c * inv), q3 = (int)rintf(d * inv);
    return (unsigned int)(q0 & 0xFF) | ((unsigned int)(q1 & 0xFF) << 8)
         | ((unsigned int)(q2 & 0xFF) << 16) | ((unsigned int)(q3 & 0xFF) << 24);
}
__device__ __forceinline__ void dec16(const unsigned int* h, float* x) {
    #pragma unroll
    for (int w4 = 0; w4 < 4; ++w4) {
        unsigned int u = h[w4];
        x[w4 * 4 + 0] = (float)((int)(u << 24) >> 24);
        x[w4 * 4 + 1] = (float)((int)(u << 16) >> 24);
        x[w4 * 4 + 2] = (float)((int)(u << 8)  >> 24);
        x[w4 * 4 + 3] = (float)((int)u >> 24);
    }
}

// ---------------------------------------------------------------------------
// Fused prologue. Blocks 0..1023: streaming fp32 -> int8 quantization of both
// feature arrays (per-node per-32-dim-block scales; NT loads keep fp32 out of
// L3). Blocks 1024..3071: Wc prep (bf16, k<256: W_ih+W_hh; k>=256: W_ih) and
// bsum = b_ih + b_hh. grid: 3072 x 256.
// ---------------------------------------------------------------------------
__global__ __launch_bounds__(256) void k_cvtprep(
    const float* __restrict__ fA, const float* __restrict__ fB,
    unsigned int* __restrict__ oA, unsigned int* __restrict__ oB,
    float* __restrict__ scA, float* __restrict__ scB,
    const float* __restrict__ WihA, const float* __restrict__ WhhA,
    const float* __restrict__ bihA, const float* __restrict__ bhhA,
    const float* __restrict__ WihB, const float* __restrict__ WhhB,
    const float* __restrict__ bihB, const float* __restrict__ bhhB,
    unsigned short* __restrict__ Wc, float* __restrict__ bsum, int doquant)
{
    int bid = blockIdx.x;
    if (bid < 1024) {
        if (!doquant) return;
        int wid  = bid * 4 + (threadIdx.x >> 6);   // 0..4095
        int lane = threadIdx.x & 63;
        int grp  = lane >> 3;
        #pragma unroll 2
        for (int n = wid; n < 65536; n += 4096) {
            accv_t v = __builtin_nontemporal_load((const accv_t*)(fA + (size_t)n * 256) + lane);
            float m = fmaxf(fmaxf(fabsf(v[0]), fabsf(v[1])), fmaxf(fabsf(v[2]), fabsf(v[3])));
            m = fmaxf(m, __shfl_xor(m, 1));
            m = fmaxf(m, __shfl_xor(m, 2));
            m = fmaxf(m, __shfl_xor(m, 4));
            float inv = (m > 0.0f) ? 127.0f / m : 0.0f;
            oA[(size_t)n * 64 + lane] = packq(v[0], v[1], v[2], v[3], inv);
            if ((lane & 7) == 0) scA[(size_t)n * 8 + grp] = m * (1.0f / 127.0f);
        }
        #pragma unroll 2
        for (int n = wid; n < 131072; n += 4096) {
            accv_t v = __builtin_nontemporal_load((const accv_t*)(fB + (size_t)n * 256) + lane);
            float m = fmaxf(fmaxf(fabsf(v[0]), fabsf(v[1])), fmaxf(fabsf(v[2]), fabsf(v[3])));
            m = fmaxf(m, __shfl_xor(m, 1));
            m = fmaxf(m, __shfl_xor(m, 2));
            m = fmaxf(m, __shfl_xor(m, 4));
            float inv = (m > 0.0f) ? 127.0f / m : 0.0f;
            oB[(size_t)n * 64 + lane] = packq(v[0], v[1], v[2], v[3], inv);
            if ((lane & 7) == 0) scB[(size_t)n * 8 + grp] = m * (1.0f / 127.0f);
        }
    } else {
        int pid = bid - 1024;
        int set = pid >> 10;
        int n   = pid & 1023;
        int k   = threadIdx.x;                     // 0..255
        const float* Wih = set ? WihB : WihA;
        const float* Whh = set ? WhhB : WhhA;
        float w1 = Wih[(size_t)n * 512 + k] + Whh[(size_t)n * 256 + k];
        float w2 = Wih[(size_t)n * 512 + 256 + k];
        size_t base = ((size_t)(set << 10) + n) * 512;
        Wc[base + k]       = f2bf(w1);
        Wc[base + 256 + k] = f2bf(w2);
        if (k == 0) {
            const float* bih = set ? bihB : bihA;
            const float* bhh = set ? bhhB : bhhA;
            bsum[(set << 10) + n] = bih[n] + bhh[n];
        }
    }
}

// ---------------------------------------------------------------------------
// LSTM gate GEMM: gates_bf[set][m][n] (bf16) = hr_bf @ Wc^T + bsum.
// M=1024, N=1024, K=512 per set. BM=64, BN=64, BK=32, 4 waves (32x32 each),
// 16x16x32 bf16 MFMA. grid: 512 blocks (set = bid>>8) -> 2 blocks/CU.
// A (hr) is already bf16 -> direct ushort8 staging, no cvt in hot loop.
// ---------------------------------------------------------------------------
__global__ __launch_bounds__(256) void k_gemm(
    const unsigned short* __restrict__ hrb, const unsigned short* __restrict__ Wc,
    const float* __restrict__ bsum, unsigned short* __restrict__ gates)
{
    __shared__ unsigned short sA[64 * 40];
    __shared__ unsigned short sB[64 * 40];

    int set   = blockIdx.x >> 8;
    int qq    = blockIdx.x & 255;
    int mbase = (qq >> 4) * 64;
    int nbase = (qq & 15) * 64;
    int t     = threadIdx.x;
    int lane  = t & 63;
    int w     = t >> 6;
    int wrow  = (w >> 1) * 32;
    int wcol  = (w & 1) * 32;
    int l15   = lane & 15;
    int khalf = (lane >> 4) * 8;

    const unsigned short* Am = hrb + (size_t)(set << 10) * 512;
    const unsigned short* Bm = Wc  + (size_t)(set << 10) * 512;

    accv_t acc[2][2];
    #pragma unroll
    for (int i = 0; i < 2; ++i)
        #pragma unroll
        for (int j = 0; j < 2; ++j)
            acc[i][j] = (accv_t){0.f, 0.f, 0.f, 0.f};

    int srow = t >> 2;
    int skc  = (t & 3) * 8;
    for (int k0 = 0; k0 < 512; k0 += 32) {
        *(upk8_t*)&sA[srow * 40 + skc] =
            *(const upk8_t*)&Am[(size_t)(mbase + srow) * 512 + k0 + skc];
        *(upk8_t*)&sB[srow * 40 + skc] =
            *(const upk8_t*)&Bm[(size_t)(nbase + srow) * 512 + k0 + skc];
        __syncthreads();

        bfrag_t a_f[2], b_f[2];
        #pragma unroll
        for (int i = 0; i < 2; ++i)
            a_f[i] = *(const bfrag_t*)&sA[(wrow + i * 16 + l15) * 40 + khalf];
        #pragma unroll
        for (int j = 0; j < 2; ++j)
            b_f[j] = *(const bfrag_t*)&sB[(wcol + j * 16 + l15) * 40 + khalf];
        #pragma unroll
        for (int i = 0; i < 2; ++i)
            #pragma unroll
            for (int j = 0; j < 2; ++j)
                acc[i][j] = __builtin_amdgcn_mfma_f32_16x16x32_bf16(a_f[i], b_f[j], acc[i][j], 0, 0, 0);
        __syncthreads();
    }

    int r4 = (lane >> 4) * 4;
    #pragma unroll
    for (int i = 0; i < 2; ++i) {
        #pragma unroll
        for (int j = 0; j < 2; ++j) {
            int col  = nbase + wcol + j * 16 + l15;
            float bs = bsum[(set << 10) + col];
            #pragma unroll
            for (int v = 0; v < 2; ++v) {
                int row0 = mbase + wrow + i * 16 + r4 + 2 * v;
                gates[((size_t)(set << 10) + row0) * 1024 + col]     = f2bf(acc[i][j][2 * v] + bs);
                gates[((size_t)(set << 10) + row0 + 1) * 1024 + col] = f2bf(acc[i][j][2 * v + 1] + bs);
            }
        }
    }
}

// ---------------------------------------------------------------------------
// Attention, templated on MODE / LAST:
//  MODE 1: read int8 copy + per-32-dim-block scales; MODE 2: fp32 fallback.
//  LAST: write q_star (and feat_global tail) straight to out (f32).
// gates read bf16; hr written bf16 (only consumed by the bf16 GEMM, so
// numerically identical to the old f32-hr + in-gemm f2bf).
// grid: 2048 blocks (0..1023 bonds, 1024..2047 atoms), 256 threads.
// ---------------------------------------------------------------------------
template <int MODE, bool LAST>
__global__ __launch_bounds__(256) void k_attn(
    const float* __restrict__ featA, const float* __restrict__ featB,
    const unsigned int* __restrict__ i8A, const unsigned int* __restrict__ i8B,
    const float* __restrict__ scA, const float* __restrict__ scB,
    const unsigned short* __restrict__ gates, const float* __restrict__ bsum,
    unsigned short* __restrict__ hrb, float* __restrict__ cst,
    const float* __restrict__ fgp, float* __restrict__ outp, int iter)
{
    __shared__ float qv[256];
    __shared__ float sw_s[16], cw_s[16];
    __shared__ float racc_s[16][260];

    int bid = blockIdx.x;
    int set = (bid < 1024) ? 1 : 0;          // bonds first (2x work)
    int b   = bid & 1023;
    int K   = set ? KBOND : KATOM;
    int t = threadIdx.x;
    size_t sb = (size_t)(set << 10) + b;
    size_t ob = (size_t)b * 1152 + (set ? 512 : 0);

    // ---- stage 1: LSTM elementwise, d = t ----
    {
        int d = t;
        float gi, gf, gg, go, cold;
        if (iter == 0) {
            gi = bsum[(set << 10) + d];
            gf = bsum[(set << 10) + 256 + d];
            gg = bsum[(set << 10) + 512 + d];
            go = bsum[(set << 10) + 768 + d];
            cold = 0.0f;
        } else {
            const unsigned short* gp = gates + sb * 1024;
            gi = bf2f(gp[d]); gf = bf2f(gp[256 + d]);
            gg = bf2f(gp[512 + d]); go = bf2f(gp[768 + d]);
            cold = cst[sb * 256 + d];
        }
        float cn = sigm(gf) * cold + sigm(gi) * tanh_f(gg);
        float h  = sigm(go) * tanh_f(cn);
        if (LAST) { outp[ob + d] = h; }
        else      { cst[sb * 256 + d] = cn; hrb[sb * 512 + d] = f2bf(h); }
        qv[d] = h;
    }
    __syncthreads();

    int lane = t & 63;
    int wv   = t >> 6;
    int g    = lane >> 4;
    int s    = lane & 15;
    int npw  = K >> 2;
    int nq   = npw >> 2;
    int node0 = wv * npw + g;
    float C = 0.0f, sacc = 0.0f;
    int pid = (wv << 2) | g;

    if (MODE == 1) {
        // int8 read path: per node 1 uint4 (16 int8, dims 16s..16s+16) + scale
        const unsigned int* fb = (set ? i8B : i8A)
                               + ((size_t)b * K + node0) * 64 + s * 4;
        const float* scp = (set ? scB : scA)
                         + ((size_t)b * K + node0) * 8 + (s >> 1);

        float qr[16];
        #pragma unroll
        for (int j = 0; j < 16; ++j) qr[j] = qv[s * 16 + j];
        float r[16];
        #pragma unroll
        for (int j = 0; j < 16; ++j) r[j] = 0.0f;

        #pragma unroll 4
        for (int qd = 0; qd < nq; ++qd) {
            u32x4 hx = *(const u32x4*)(fb + (size_t)qd * 256);
            float sc = scp[(size_t)qd * 32];
            float x[16];
            dec16((const unsigned int*)&hx, x);
            float e = 0.0f;
            #pragma unroll
            for (int j = 0; j < 16; ++j) e += x[j] * qr[j];
            e *= sc;
            e += __shfl_xor(e, 1);
            e += __shfl_xor(e, 2);
            e += __shfl_xor(e, 4);
            e += __shfl_xor(e, 8);
            float w = (qd == 0) ? 1.0f : __expf(e - C);
            if (qd == 0) C = e;
            sacc += w;
            float wl = w * sc;
            #pragma unroll
            for (int j = 0; j < 16; ++j) r[j] += wl * x[j];
        }
        #pragma unroll
        for (int j = 0; j < 16; j += 4)
            *(float4*)&racc_s[pid][s * 16 + j] = *(float4*)&r[j];
    } else {
        // fp32 fallback: lane owns dims {c*64 + s*4..+4}, c=0..3
        const float* feat = set ? featB : featA;
        const float* fb = feat + ((size_t)b * K + node0) * 256 + s * 4;
        float4 q0 = *(const float4*)&qv[s*4];
        float4 q1 = *(const float4*)&qv[64  + s*4];
        float4 q2 = *(const float4*)&qv[128 + s*4];
        float4 q3 = *(const float4*)&qv[192 + s*4];
        float4 r0 = make_float4(0.f,0.f,0.f,0.f), r1 = r0, r2 = r0, r3 = r0;
        #pragma unroll 2
        for (int qd = 0; qd < nq; ++qd) {
            const float* p = fb + (size_t)qd * 1024;
            float4 x0 = *(const float4*)(p);
            float4 x1 = *(const float4*)(p + 64);
            float4 x2 = *(const float4*)(p + 128);
            float4 x3 = *(const float4*)(p + 192);
            float e = x0.x*q0.x + x0.y*q0.y + x0.z*q0.z + x0.w*q0.w
                    + x1.x*q1.x + x1.y*q1.y + x1.z*q1.z + x1.w*q1.w
                    + x2.x*q2.x + x2.y*q2.y + x2.z*q2.z + x2.w*q2.w
                    + x3.x*q3.x + x3.y*q3.y + x3.z*q3.z + x3.w*q3.w;
            e += __shfl_xor(e, 1); e += __shfl_xor(e, 2);
            e += __shfl_xor(e, 4); e += __shfl_xor(e, 8);
            float w = (qd == 0) ? 1.0f : __expf(e - C);
            if (qd == 0) C = e;
            sacc += w;
            r0.x += w*x0.x; r0.y += w*x0.y; r0.z += w*x0.z; r0.w += w*x0.w;
            r1.x += w*x1.x; r1.y += w*x1.y; r1.z += w*x1.z; r1.w += w*x1.w;
            r2.x += w*x2.x; r2.y += w*x2.y; r2.z += w*x2.z; r2.w += w*x2.w;
            r3.x += w*x3.x; r3.y += w*x3.y; r3.z += w*x3.z; r3.w += w*x3.w;
        }
        *(float4*)&racc_s[pid][s*4]       = r0;
        *(float4*)&racc_s[pid][64  + s*4] = r1;
        *(float4*)&racc_s[pid][128 + s*4] = r2;
        *(float4*)&racc_s[pid][192 + s*4] = r3;
    }
    if (s == 0) { sw_s[pid] = sacc; cw_s[pid] = C; }
    __syncthreads();

    // ---- stage 3: pivot-reconciled merge of 16 partials, d = t ----
    {
        float Cm = cw_s[0];
        #pragma unroll
        for (int p2 = 1; p2 < 16; ++p2) Cm = fmaxf(Cm, cw_s[p2]);
        float S = 0.0f, r = 0.0f;
        #pragma unroll
        for (int p2 = 0; p2 < 16; ++p2) {
            float f = __expf(cw_s[p2] - Cm);
            S += sw_s[p2] * f;
            r += racc_s[p2][t] * f;
        }
        float rv = r / S;
        if (LAST) {
            outp[ob + 256 + t] = rv;
            if (set && t < 128)
                outp[(size_t)b * 1152 + 1024 + t] = fgp[(size_t)b * 128 + t];
        } else {
            hrb[sb * 512 + 256 + t] = f2bf(rv);
        }
    }
}

extern "C" void kernel_launch(void* const* d_in, const int* in_sizes, int n_in,
                              void* d_out, int out_size, void* d_ws, size_t ws_size,
                              hipStream_t stream) {
    const float* feat_atom   = (const float*)d_in[0];
    const float* feat_bond   = (const float*)d_in[2];
    const float* feat_global = (const float*)d_in[4];
    const float* WihA = (const float*)d_in[5];
    const float* WhhA = (const float*)d_in[6];
    const float* bihA = (const float*)d_in[7];
    const float* bhhA = (const float*)d_in[8];
    const float* WihB = (const float*)d_in[9];
    const float* WhhB = (const float*)d_in[10];
    const float* bihB = (const float*)d_in[11];
    const float* bhhB = (const float*)d_in[12];
    float* out = (float*)d_out;

    // workspace layout (bytes)
    char* ws = (char*)d_ws;
    unsigned short* Wc    = (unsigned short*)(ws + 0);        // 2,097,152
    float*          bsum  = (float*)(ws + 2097152);           // 8,192
    unsigned short* gates = (unsigned short*)(ws + 2105344);  // 4,194,304 (bf16)
    unsigned short* hrb   = (unsigned short*)(ws + 6299648);  // 2,097,152 (bf16)
    float*          cst   = (float*)(ws + 8396800);           // 2,097,152
    unsigned int*   i8A   = (unsigned int*)(ws + 10493952);   // 16,777,216
    unsigned int*   i8B   = (unsigned int*)(ws + 27271168);   // 33,554,432
    float*          scA   = (float*)(ws + 60825600);          // 2,097,152
    float*          scB   = (float*)(ws + 62922752);          // 4,194,304
    const size_t WS_NEED = 62922752 + 4194304;                // 67,117,056
    (void)in_sizes; (void)n_in; (void)out_size;

    bool i8 = (ws_size >= WS_NEED);

    k_cvtprep<<<3072, 256, 0, stream>>>(feat_atom, feat_bond, i8A, i8B, scA, scB,
                                        WihA, WhhA, bihA, bhhA,
                                        WihB, WhhB, bihB, bhhB,
                                        Wc, bsum, i8 ? 1 : 0);
    if (i8) {
        k_attn<1, false><<<2048, 256, 0, stream>>>(feat_atom, feat_bond, i8A, i8B,
                                                   scA, scB, gates, bsum, hrb, cst,
                                                   feat_global, out, 0);
        for (int it = 1; it < 5; ++it) {
            k_gemm<<<512, 256, 0, stream>>>(hrb, Wc, bsum, gates);
            k_attn<1, false><<<2048, 256, 0, stream>>>(feat_atom, feat_bond, i8A, i8B,
                                                       scA, scB, gates, bsum, hrb, cst,
                                                       feat_global, out, it);
        }
        k_gemm<<<512, 256, 0, stream>>>(hrb, Wc, bsum, gates);
        k_attn<1, true><<<2048, 256, 0, stream>>>(feat_atom, feat_bond, i8A, i8B,
                                                  scA, scB, gates, bsum, hrb, cst,
                                                  feat_global, out, 5);
    } else {
        k_attn<2, false><<<2048, 256, 0, stream>>>(feat_atom, feat_bond, 0, 0, 0, 0,
                                                   gates, bsum, hrb, cst,
                                                   feat_global, out, 0);
        for (int it = 1; it < 5; ++it) {
            k_gemm<<<512, 256, 0, stream>>>(hrb, Wc, bsum, gates);
            k_attn<2, false><<<2048, 256, 0, stream>>>(feat_atom, feat_bond, 0, 0, 0, 0,
                                                       gates, bsum, hrb, cst,
                                                       feat_global, out, it);
        }
        k_gemm<<<512, 256, 0, stream>>>(hrb, Wc, bsum, gates);
        k_attn<2, true><<<2048, 256, 0, stream>>>(feat_atom, feat_bond, 0, 0, 0, 0,
                                                  gates, bsum, hrb, cst,
                                                  feat_global, out, 5);
    }
}